// Round 1
// baseline (27377.960 us; speedup 1.0000x reference)
//
#include <hip/hip_runtime.h>
#include <math.h>

// JordanRNN: B=128, T=2048, I=128, H=256, O=64.
// 128 WGs = 8 batch-columns (16 batch, one per XCD) x 16 hidden-slices (16 units).
// Weights register-resident as fp16 MFMA fragments; h/y exchanged via MALL with
// per-WG monotonic flags (release store / acquire poll). One wave per WG.

#define BATCH 128
#define TSTEPS 2048
#define ISZ 128
#define HSZ 256
#define OSZ 64

typedef _Float16 half8 __attribute__((ext_vector_type(8)));
typedef float f32x4 __attribute__((ext_vector_type(4)));

#define AGENT __HIP_MEMORY_SCOPE_AGENT

__device__ __forceinline__ f32x4 mfma16(half8 a, half8 b, f32x4 c) {
  return __builtin_amdgcn_mfma_f32_16x16x32_f16(a, b, c, 0, 0, 0);
}

// ws layout:
//   hbuf : 2 * 128 * 256 fp16   = 131072 B   @ 0
//   ybuf : 2 * 128 *  64 fp16   =  32768 B   @ 131072
//   hflag: 8 cols * 16 WGs * u32 =   512 B   @ 163840
//   yflag: 8 cols *  4 WGs * u32 =   128 B   @ 164352
//   total 164480 B (memset to 0 each launch)

__global__ __launch_bounds__(64, 1)
void jordan_rnn(const float* __restrict__ xg,
                const float* __restrict__ w_ih,
                const float* __restrict__ w_hh,
                const float* __restrict__ b_ih,
                const float* __restrict__ b_hh,
                const float* __restrict__ fc_w,
                const float* __restrict__ fc_b,
                float* __restrict__ out,
                unsigned char* __restrict__ ws)
{
  const int lane = threadIdx.x;        // 64 threads = 1 wave
  const int c    = blockIdx.x & 7;     // batch column (XCD-aligned: bid%8)
  const int j    = blockIdx.x >> 3;    // hidden slice 0..15
  const int n    = lane & 15;          // MFMA N index (unit / weight row / out col)
  const int quad = lane >> 4;          // MFMA quad
  const int u0   = j * 16;             // first hidden unit of this slice
  const int b0   = c * 16;             // first batch row of this column

  _Float16* hbuf = (_Float16*)ws;                      // [2][128][256]
  _Float16* ybuf = (_Float16*)(ws + 131072);           // [2][128][64]
  unsigned int* hflag = (unsigned int*)(ws + 163840);  // [8][16]
  unsigned int* yflag = (unsigned int*)(ws + 164352);  // [8][4]
  unsigned int* myh = hflag + c * 16;
  unsigned int* myy = yflag + c * 4;

  // A-operand staging: [m][k], k: 0..127 = x(t), 128..191 = y(t-1), 192..447 = h(t-1)
  // stride 456 fp16 (912 B) -> 16B-aligned rows, 2-way-max LDS bank aliasing (free)
  __shared__ _Float16 act[16][456];
  __shared__ _Float16 hout[16][16];

  // ---- weight fragments, register-resident (fp16). B-frag: lane holds W[n][kk*32+quad*8+q]
  half8 wr[14], wz[14], win[6], whn[8], wfc[8];
  {
    const int kq = quad * 8;
    const int ur = u0 + n;           // r-gate row
    const int uz = 256 + u0 + n;     // z-gate row
    const int un = 512 + u0 + n;     // n-gate row
#pragma unroll
    for (int kk = 0; kk < 6; ++kk) {               // k 0..191: w_ih (x|y)
      const float* pr = w_ih + ur * 192 + kk * 32 + kq;
      const float* pz = w_ih + uz * 192 + kk * 32 + kq;
      const float* pn = w_ih + un * 192 + kk * 32 + kq;
#pragma unroll
      for (int q = 0; q < 8; ++q) {
        wr[kk][q]  = (_Float16)pr[q];
        wz[kk][q]  = (_Float16)pz[q];
        win[kk][q] = (_Float16)pn[q];
      }
    }
#pragma unroll
    for (int kk = 0; kk < 8; ++kk) {               // k 192..447: w_hh
      const float* pr = w_hh + ur * 256 + kk * 32 + kq;
      const float* pz = w_hh + uz * 256 + kk * 32 + kq;
      const float* pn = w_hh + un * 256 + kk * 32 + kq;
#pragma unroll
      for (int q = 0; q < 8; ++q) {
        wr[6 + kk][q] = (_Float16)pr[q];
        wz[6 + kk][q] = (_Float16)pz[q];
        whn[kk][q]    = (_Float16)pn[q];
      }
    }
    if (j < 4) {                                   // y-producer WGs: fc slice cols [j*16, j*16+16)
#pragma unroll
      for (int kk = 0; kk < 8; ++kk) {
        const float* pf = fc_w + (j * 16 + n) * 256 + kk * 32 + kq;
#pragma unroll
        for (int q = 0; q < 8; ++q) wfc[kk][q] = (_Float16)pf[q];
      }
    }
  }
  const float br   = b_ih[u0 + n] + b_hh[u0 + n];
  const float bz   = b_ih[256 + u0 + n] + b_hh[256 + u0 + n];
  const float bin_ = b_ih[512 + u0 + n];           // kept separate: n-gate is i_n + r*h_n
  const float bhn  = b_hh[512 + u0 + n];
  const float fcb  = (j < 4) ? fc_b[j * 16 + n] : 0.f;

  for (int t = 1; t <= TSTEPS; ++t) {
    const unsigned int tgt = (unsigned int)(t - 1);

    // ---- 1) wait peers: h(t-1) published (acquire => cache inv before plain loads)
    if (t > 1) {
      for (;;) {
        unsigned int f = (lane < 16)
            ? __hip_atomic_load(&myh[lane], __ATOMIC_ACQUIRE, AGENT) : tgt;
        if (__all((int)(f >= tgt))) break;
      }
    }

    // ---- 2) stage h(t-1) (fp16, vectorized) and x(t-1) (fp32 -> fp16)
    {
      const uint4* hs4 = (const uint4*)(hbuf + (size_t)((t - 1) & 1) * (BATCH * HSZ));
#pragma unroll
      for (int i = 0; i < 8; ++i) {
        int flat = lane + 64 * i;                  // 0..511 ; row = 32 uint4
        int m = flat >> 5, q4 = flat & 31;
        uint4 v = hs4[(b0 + m) * 32 + q4];
        *(uint4*)&act[m][192 + q4 * 8] = v;
      }
#pragma unroll
      for (int i = 0; i < 8; ++i) {
        int flat = lane + 64 * i;                  // 0..511 ; row = 32 float4
        int m = flat >> 5, p4 = flat & 31;
        const float4 v = *(const float4*)(xg + ((size_t)(b0 + m) * TSTEPS + (t - 1)) * ISZ + p4 * 4);
        union { _Float16 h[4]; uint2 u; } pk;
        pk.h[0] = (_Float16)v.x; pk.h[1] = (_Float16)v.y;
        pk.h[2] = (_Float16)v.z; pk.h[3] = (_Float16)v.w;
        *(uint2*)&act[m][p4 * 4] = pk.u;
      }
    }
    __syncthreads();

    // ---- 3) y producers (j<4): y(t-1) = tanh(h(t-1) @ fc_w.T + fc_b), publish ASAP
    if (j < 4 && t >= 2) {
      f32x4 accy = {0.f, 0.f, 0.f, 0.f};
#pragma unroll
      for (int kk = 0; kk < 8; ++kk) {
        half8 af = *(const half8*)&act[n][192 + kk * 32 + quad * 8];  // n plays m here
        accy = mfma16(af, wfc[kk], accy);
      }
#pragma unroll
      for (int r = 0; r < 4; ++r)
        hout[quad * 4 + r][n] = (_Float16)tanhf(accy[r] + fcb);
      __syncthreads();
      unsigned int* yd = (unsigned int*)(ybuf + (size_t)((t - 1) & 1) * (BATCH * OSZ));
#pragma unroll
      for (int i = 0; i < 2; ++i) {
        int d = lane + 64 * i;                     // 0..127 dwords; 8 dwords/slice-row
        int m = d >> 3, dd = d & 7;
        unsigned int v = *(const unsigned int*)&hout[m][dd * 2];
        __hip_atomic_store(&yd[(b0 + m) * 32 + j * 8 + dd], v, __ATOMIC_RELAXED, AGENT);
      }
      __syncthreads();                             // drain wave stores before flag
      if (lane == 0)
        __hip_atomic_store(&myy[j], tgt, __ATOMIC_RELEASE, AGENT);
    }

    // ---- 4) gate GEMMs, K-steps not needing y first: x (0..3), h (6..13)
    f32x4 accR = {0.f,0.f,0.f,0.f}, accZ = {0.f,0.f,0.f,0.f};
    f32x4 accIN = {0.f,0.f,0.f,0.f}, accHN = {0.f,0.f,0.f,0.f};
#pragma unroll
    for (int kk = 0; kk < 4; ++kk) {
      half8 af = *(const half8*)&act[n][kk * 32 + quad * 8];
      accR  = mfma16(af, wr[kk],  accR);
      accZ  = mfma16(af, wz[kk],  accZ);
      accIN = mfma16(af, win[kk], accIN);
    }
#pragma unroll
    for (int kk = 6; kk < 14; ++kk) {
      half8 af = *(const half8*)&act[n][kk * 32 + quad * 8];
      accR  = mfma16(af, wr[kk],     accR);
      accZ  = mfma16(af, wz[kk],     accZ);
      accHN = mfma16(af, whn[kk - 6], accHN);
    }

    // ---- 5) wait y(t-1), stage it, finish K-steps 4..5
    if (t > 1) {
      for (;;) {
        unsigned int f = (lane < 4)
            ? __hip_atomic_load(&myy[lane], __ATOMIC_ACQUIRE, AGENT) : tgt;
        if (__all((int)(f >= tgt))) break;
      }
    }
    {
      const uint4* ys4 = (const uint4*)(ybuf + (size_t)((t - 1) & 1) * (BATCH * OSZ));
#pragma unroll
      for (int i = 0; i < 2; ++i) {
        int flat = lane + 64 * i;                  // 0..127 ; row = 8 uint4
        int m = flat >> 3, q4 = flat & 7;
        uint4 v = ys4[(b0 + m) * 8 + q4];
        *(uint4*)&act[m][128 + q4 * 8] = v;
      }
    }
    __syncthreads();
#pragma unroll
    for (int kk = 4; kk < 6; ++kk) {
      half8 af = *(const half8*)&act[n][kk * 32 + quad * 8];
      accR  = mfma16(af, wr[kk],  accR);
      accZ  = mfma16(af, wz[kk],  accZ);
      accIN = mfma16(af, win[kk], accIN);
    }

    // ---- 6) gating (fp32), straight from accumulators (C-layout: m=quad*4+r, n=lane&15)
#pragma unroll
    for (int r = 0; r < 4; ++r) {
      int m = quad * 4 + r;
      float rg = 1.f / (1.f + __expf(-(accR[r] + br)));
      float zg = 1.f / (1.f + __expf(-(accZ[r] + bz)));
      float nn = tanhf(accIN[r] + bin_ + rg * (accHN[r] + bhn));
      float hp = (float)act[m][192 + u0 + n];      // h(t-1) for this unit
      hout[m][n] = (_Float16)((1.f - zg) * nn + zg * hp);
    }
    __syncthreads();

    // ---- 7) publish h(t) slice + flag
    {
      unsigned int* hd = (unsigned int*)(hbuf + (size_t)(t & 1) * (BATCH * HSZ));
#pragma unroll
      for (int i = 0; i < 2; ++i) {
        int d = lane + 64 * i;                     // 0..127 dwords; 8 dwords/slice-row
        int m = d >> 3, dd = d & 7;
        unsigned int v = *(const unsigned int*)&hout[m][dd * 2];
        __hip_atomic_store(&hd[(b0 + m) * 128 + j * 8 + dd], v, __ATOMIC_RELAXED, AGENT);
      }
    }
    __syncthreads();                               // drain wave stores before flag
    if (lane == 0)
      __hip_atomic_store(&myh[j], (unsigned int)t, __ATOMIC_RELEASE, AGENT);
  }

  // ---- final: y(T) = tanh(h(T) @ fc_w.T + fc_b) -> d_out (fp32)
  if (j < 4) {
    const unsigned int tgt = (unsigned int)TSTEPS;
    for (;;) {
      unsigned int f = (lane < 16)
          ? __hip_atomic_load(&myh[lane], __ATOMIC_ACQUIRE, AGENT) : tgt;
      if (__all((int)(f >= tgt))) break;
    }
    const uint4* hs4 = (const uint4*)(hbuf + (size_t)(TSTEPS & 1) * (BATCH * HSZ));
#pragma unroll
    for (int i = 0; i < 8; ++i) {
      int flat = lane + 64 * i;
      int m = flat >> 5, q4 = flat & 31;
      uint4 v = hs4[(b0 + m) * 32 + q4];
      *(uint4*)&act[m][192 + q4 * 8] = v;
    }
    __syncthreads();
    f32x4 accy = {0.f, 0.f, 0.f, 0.f};
#pragma unroll
    for (int kk = 0; kk < 8; ++kk) {
      half8 af = *(const half8*)&act[n][192 + kk * 32 + quad * 8];
      accy = mfma16(af, wfc[kk], accy);
    }
#pragma unroll
    for (int r = 0; r < 4; ++r)
      out[(size_t)(b0 + quad * 4 + r) * 64 + j * 16 + n] = tanhf(accy[r] + fcb);
  }
}

extern "C" void kernel_launch(void* const* d_in, const int* in_sizes, int n_in,
                              void* d_out, int out_size, void* d_ws, size_t ws_size,
                              hipStream_t stream) {
  // zero flags + h/y double buffers (h0 = 0, y0 = 0, flags = "step 0 done")
  hipMemsetAsync(d_ws, 0, 164480, stream);
  jordan_rnn<<<dim3(128), dim3(64), 0, stream>>>(
      (const float*)d_in[0],   // x
      (const float*)d_in[1],   // w_ih
      (const float*)d_in[2],   // w_hh
      (const float*)d_in[3],   // b_ih
      (const float*)d_in[4],   // b_hh
      (const float*)d_in[5],   // fc_w
      (const float*)d_in[6],   // fc_b
      (float*)d_out,
      (unsigned char*)d_ws);
}

// Round 2
// 12483.301 us; speedup vs baseline: 2.1932x; 2.1932x over previous
//
#include <hip/hip_runtime.h>
#include <math.h>

// JordanRNN B=128,T=2048,I=128,H=256,O=64.
// 16 WGs x 512 thr: 8 batch-columns x 2 hidden-halves. Each of 8 waves/WG owns a
// 16-unit slice (weights register-resident fp16). One cross-WG MALL hop per step
// (partner h-half, 4KB); y computed redundantly per WG (own-half fc partial kept
// in registers across the step boundary). Relaxed spin + single acquire fence.

#define TSTEPS 2048
#define ISZ 128

typedef _Float16 half8 __attribute__((ext_vector_type(8)));
typedef float f32x4 __attribute__((ext_vector_type(4)));
#define AGENT __HIP_MEMORY_SCOPE_AGENT

__device__ __forceinline__ f32x4 mfma16(half8 a, half8 b, f32x4 c) {
  return __builtin_amdgcn_mfma_f32_16x16x32_f16(a, b, c, 0, 0, 0);
}
__device__ __forceinline__ float sigm(float x) {
  return __builtin_amdgcn_rcpf(1.f + __expf(-x));
}
__device__ __forceinline__ float tanh_fast(float x) {
  return 1.f - 2.f * __builtin_amdgcn_rcpf(1.f + __expf(2.f * x));
}

// ws: payload [2 parity][16 wg][16 rows][128 halves] = 131072 B @0; flags u32[16] @131072

__global__ __launch_bounds__(512, 2)
void jordan_rnn(const float* __restrict__ xg, const float* __restrict__ w_ih,
                const float* __restrict__ w_hh, const float* __restrict__ b_ih,
                const float* __restrict__ b_hh, const float* __restrict__ fc_w,
                const float* __restrict__ fc_b, float* __restrict__ out,
                unsigned char* __restrict__ ws)
{
  const int tid  = threadIdx.x;
  const int lane = tid & 63;
  const int wv   = tid >> 6;          // wave 0..7
  const int n    = lane & 15;
  const int quad = lane >> 4;
  const int col  = blockIdx.x & 7;    // batch column (both halves same XCD: wg^8)
  const int p    = blockIdx.x >> 3;   // hidden half 0/1
  const int wg   = blockIdx.x;
  const int u0   = p * 128 + wv * 16; // this wave's unit slice (absolute in H)
  const int b0   = col * 16;

  unsigned char* pay = ws;
  unsigned int* flags = (unsigned int*)(ws + 131072);

  // act cols: 0..127 = x(t), 128..191 = y(t-1), 192..447 = h(t-1)/h(t)
  __shared__ _Float16 act[16][456];
  {
    unsigned int* za = (unsigned int*)&act[0][0];
    for (int i = tid; i < 3648; i += 512) za[i] = 0u;   // y,h regions must be 0
  }

  // ---- register-resident weights (fp16 B-fragments: lane holds W[n][k32+quad*8+q])
  half8 wr[14], wz[14], win[6], whn[8], wfc[8];
  {
    const int kq = quad * 8;
    const int ur = u0 + n, uz = 256 + u0 + n, un = 512 + u0 + n;
#pragma unroll
    for (int kk = 0; kk < 6; ++kk) {            // k 0..191: w_ih (x|y)
      const float* pr = w_ih + ur * 192 + kk * 32 + kq;
      const float* pz = w_ih + uz * 192 + kk * 32 + kq;
      const float* pn = w_ih + un * 192 + kk * 32 + kq;
#pragma unroll
      for (int q = 0; q < 8; ++q) {
        wr[kk][q] = (_Float16)pr[q]; wz[kk][q] = (_Float16)pz[q]; win[kk][q] = (_Float16)pn[q];
      }
    }
#pragma unroll
    for (int kk = 0; kk < 8; ++kk) {            // k 192..447: w_hh
      const float* pr = w_hh + ur * 256 + kk * 32 + kq;
      const float* pz = w_hh + uz * 256 + kk * 32 + kq;
      const float* pn = w_hh + un * 256 + kk * 32 + kq;
#pragma unroll
      for (int q = 0; q < 8; ++q) {
        wr[6 + kk][q] = (_Float16)pr[q]; wz[6 + kk][q] = (_Float16)pz[q]; whn[kk][q] = (_Float16)pn[q];
      }
    }
    if (wv < 4) {                               // y-waves: fc_w N-slice wv*16, ALL K
#pragma unroll
      for (int kk = 0; kk < 8; ++kk) {
        const float* pf = fc_w + (wv * 16 + n) * 256 + kk * 32 + kq;
#pragma unroll
        for (int q = 0; q < 8; ++q) wfc[kk][q] = (_Float16)pf[q];
      }
    }
  }
  const float br   = b_ih[u0 + n] + b_hh[u0 + n];
  const float bz   = b_ih[256 + u0 + n] + b_hh[256 + u0 + n];
  const float bin_ = b_ih[512 + u0 + n];
  const float bhn  = b_hh[512 + u0 + n];
  const float fcb  = (wv < 4) ? fc_b[wv * 16 + n] : 0.f;

  float hprev[4] = {0.f, 0.f, 0.f, 0.f};        // h(t-1) for (m=quad*4+r, u0+n), fp32
  f32x4 accy = {0.f, 0.f, 0.f, 0.f};            // own-half fc partial of y(t-1)
  __syncthreads();

  const int xm = tid >> 5, xp4 = tid & 31;      // x staging role (all 512)
  const int sm = tid >> 4, sq4 = tid & 15;      // h stage/publish role (tid<256)

  for (int t = 1; t <= TSTEPS; ++t) {
    // x(t-1) prefetch — in flight during the poll
    float4 xv = *(const float4*)(xg + ((size_t)(b0 + xm) * TSTEPS + (t - 1)) * (size_t)ISZ + xp4 * 4);

    // ---- single cross-WG hop: partner h(t-1)
    const unsigned int tgt = (unsigned int)(t - 1);
    while (__hip_atomic_load(&flags[wg ^ 8], __ATOMIC_RELAXED, AGENT) < tgt) {}
    __builtin_amdgcn_fence(__ATOMIC_ACQUIRE, "agent");

    if (tid < 256) {
      const uint4* src = (const uint4*)(pay + (size_t)((t - 1) & 1) * 65536 + (size_t)(wg ^ 8) * 4096);
      uint4 v = src[sm * 16 + sq4];
      *(uint4*)&act[sm][192 + (p ^ 1) * 128 + sq4 * 8] = v;
    }
    {
      union { _Float16 h[4]; uint2 u; } pk;
      pk.h[0] = (_Float16)xv.x; pk.h[1] = (_Float16)xv.y;
      pk.h[2] = (_Float16)xv.z; pk.h[3] = (_Float16)xv.w;
      *(uint2*)&act[xm][xp4 * 4] = pk.u;
    }
    __syncthreads();  // S1: x + full h(t-1) staged

    // ---- finish y(t-1): partner-half fc MFMAs (own half already in accy)
    if (wv < 4) {
      const int kk0 = (p ^ 1) * 4;
#pragma unroll
      for (int kk = 0; kk < 4; ++kk) {
        half8 af = *(const half8*)&act[n][192 + (kk0 + kk) * 32 + quad * 8];
        accy = mfma16(af, wfc[kk0 + kk], accy);
      }
      if (t > 1) {
#pragma unroll
        for (int r = 0; r < 4; ++r)
          act[quad * 4 + r][128 + wv * 16 + n] = (_Float16)tanh_fast(accy[r] + fcb);
      }
      // t==1: y(0)=0 already in act from preamble
    }

    // ---- gate MFMAs not needing y: x (K0-3), h (K6-13)
    f32x4 aR = {0,0,0,0}, aZ = {0,0,0,0}, aIN = {0,0,0,0}, aHN = {0,0,0,0};
#pragma unroll
    for (int kk = 0; kk < 4; ++kk) {
      half8 af = *(const half8*)&act[n][kk * 32 + quad * 8];
      aR = mfma16(af, wr[kk], aR);
      aZ = mfma16(af, wz[kk], aZ);
      aIN = mfma16(af, win[kk], aIN);
    }
#pragma unroll
    for (int kk = 6; kk < 14; ++kk) {
      half8 af = *(const half8*)&act[n][kk * 32 + quad * 8];
      aR = mfma16(af, wr[kk], aR);
      aZ = mfma16(af, wz[kk], aZ);
      aHN = mfma16(af, whn[kk - 6], aHN);
    }
    __syncthreads();  // S2: y(t-1) staged
#pragma unroll
    for (int kk = 4; kk < 6; ++kk) {
      half8 af = *(const half8*)&act[n][kk * 32 + quad * 8];
      aR = mfma16(af, wr[kk], aR);
      aZ = mfma16(af, wz[kk], aZ);
      aIN = mfma16(af, win[kk], aIN);
    }
    __syncthreads();  // S2b: all h(t-1) act reads complete before overwrite

    // ---- gating (fp32), h(t) own slice -> act + hprev regs
#pragma unroll
    for (int r = 0; r < 4; ++r) {
      float rg = sigm(aR[r] + br);
      float zg = sigm(aZ[r] + bz);
      float nn = tanh_fast(aIN[r] + bin_ + rg * (aHN[r] + bhn));
      float hv = (1.f - zg) * nn + zg * hprev[r];
      hprev[r] = hv;
      act[quad * 4 + r][192 + u0 + n] = (_Float16)hv;
    }
    __syncthreads();  // S3: own half of h(t) complete in act

    // ---- own-half fc partial of y(t) (off critical path; overlaps publish)
    if (wv < 4) {
      const int kk0 = p * 4;
      accy = (f32x4){0.f, 0.f, 0.f, 0.f};
#pragma unroll
      for (int kk = 0; kk < 4; ++kk) {
        half8 af = *(const half8*)&act[n][192 + (kk0 + kk) * 32 + quad * 8];
        accy = mfma16(af, wfc[kk0 + kk], accy);
      }
    }
    // ---- publish own h(t) half + flag
    if (tid < 256) {
      uint4 v = *(const uint4*)&act[sm][192 + p * 128 + sq4 * 8];
      unsigned int* dst = (unsigned int*)(pay + (size_t)(t & 1) * 65536 + (size_t)wg * 4096)
                          + (sm * 16 + sq4) * 4;
      __hip_atomic_store(dst + 0, v.x, __ATOMIC_RELAXED, AGENT);
      __hip_atomic_store(dst + 1, v.y, __ATOMIC_RELAXED, AGENT);
      __hip_atomic_store(dst + 2, v.z, __ATOMIC_RELAXED, AGENT);
      __hip_atomic_store(dst + 3, v.w, __ATOMIC_RELAXED, AGENT);
    }
    __syncthreads();  // S4: all payload stores drained (per-wave vmcnt0 at barrier)
    if (tid == 0)
      __hip_atomic_store(&flags[wg], (unsigned int)t, __ATOMIC_RELEASE, AGENT);
  }

  // ---- epilogue: y(T) = tanh(fc @ h(T) + b); accy holds own-half partial
  while (__hip_atomic_load(&flags[wg ^ 8], __ATOMIC_RELAXED, AGENT) < (unsigned int)TSTEPS) {}
  __builtin_amdgcn_fence(__ATOMIC_ACQUIRE, "agent");
  if (tid < 256) {
    const uint4* src = (const uint4*)(pay + (size_t)(TSTEPS & 1) * 65536 + (size_t)(wg ^ 8) * 4096);
    uint4 v = src[sm * 16 + sq4];
    *(uint4*)&act[sm][192 + (p ^ 1) * 128 + sq4 * 8] = v;
  }
  __syncthreads();
  if (wv < 4 && p == 0) {                       // p==0 writes out (avoid dup-write race)
    const int kk0 = 4;                          // partner half for p=0
#pragma unroll
    for (int kk = 0; kk < 4; ++kk) {
      half8 af = *(const half8*)&act[n][192 + (kk0 + kk) * 32 + quad * 8];
      accy = mfma16(af, wfc[kk0 + kk], accy);
    }
#pragma unroll
    for (int r = 0; r < 4; ++r)
      out[(size_t)(b0 + quad * 4 + r) * 64 + wv * 16 + n] = tanh_fast(accy[r] + fcb);
  }
}

extern "C" void kernel_launch(void* const* d_in, const int* in_sizes, int n_in,
                              void* d_out, int out_size, void* d_ws, size_t ws_size,
                              hipStream_t stream) {
  hipMemsetAsync(d_ws, 0, 131136, stream);  // payload (h(0)=0) + flags ("step0 done")
  jordan_rnn<<<dim3(16), dim3(512), 0, stream>>>(
      (const float*)d_in[0], (const float*)d_in[1], (const float*)d_in[2],
      (const float*)d_in[3], (const float*)d_in[4], (const float*)d_in[5],
      (const float*)d_in[6], (float*)d_out, (unsigned char*)d_ws);
}